// Round 10
// baseline (259.978 us; speedup 1.0000x reference)
//
#include <hip/hip_runtime.h>

// BertSelfAttention: B=4 S=2048 D=1024 H=16 HD=64. Input buffers fp32 (runtime
// detected; bf16 fallback). detect -> convert to bf16 in ws (single unified
// launch) -> qkv GEMM (512-thr 8-wave, double-buffered glds16 staging, BK=64,
// XOR-seg-swizzled unpadded LDS; XCD-chunked block swizzle; Q pre-scaled by
// 0.125*log2e; V written KEY-SWIZZLED):
//   - z<2 (Q,K): SWAPPED MFMA operands (A=W, B=X) so reg index r walks hd ->
//     epilogue is 8-B packed stores
//   - z=2 (V): original orientation (r walks s) -> 8-B packed [bh][hd][SEQ]
// -> flash attention (single launch):
//   - 512-thread blocks (8 waves), 256 queries/block, 32 queries/wave
//   - __launch_bounds__(512, 2); dbuf K/V LDS; Bv tp=0,1 hoisted;
//   - mask staged once; defer-max rescale; cvt_pk packing; setprio
// R9/R10 HARDENING: explicit `s_waitcnt vmcnt(0)` before each in-loop barrier
// in qkv_bf and attn_kernel. The dbuf invariant needs the compiler's implicit
// vmcnt drain before s_barrier (m97-verified for other loop shapes); making it
// explicit is zero-cost if present and closes the only identifiable race if
// absent (R7 variant + R9 anomaly both consistent with stale-LDS fragments).

typedef short bf16x4 __attribute__((ext_vector_type(4)));
typedef short bf16x8 __attribute__((ext_vector_type(8)));
typedef float f32x4 __attribute__((ext_vector_type(4)));

#define SEQ 2048
#define DIM 1024
#define NH 16
#define HDIM 64
#define QKV_ELEMS ((size_t)64 * SEQ * HDIM)

#define WS_FLAG  50331648ull
#define WS_XBF   50331904ull
#define WS_WBF   67109120ull
#define WS_BF32  73400576ull
#define WS_NEED  73412868ull

#define LOG2E 1.4426950408889634f
#define QSCALE (0.125f * LOG2E)

static __device__ __forceinline__ unsigned short f2bf(float f) {
  union { float f; unsigned u; } x; x.f = f;
  unsigned r = x.u + 0x7fffu + ((x.u >> 16) & 1u);
  return (unsigned short)(r >> 16);
}
static __device__ __forceinline__ float bf2f(unsigned short h) {
  union { unsigned u; float f; } x; x.u = ((unsigned)h) << 16;
  return x.f;
}
// packed f32x2 -> bf16x2 (lo=a, hi=b), single HW instr
static __device__ __forceinline__ unsigned cvtpk(float a, float b) {
  unsigned r;
  asm("v_cvt_pk_bf16_f32 %0, %1, %2" : "=v"(r) : "v"(a), "v"(b));
  return r;
}
// V key-swizzle for an aligned 4-key chunk base (s % 4 == 0)
static __device__ __forceinline__ int vswz(int s) {
  return (s & ~31) | (((s >> 2) & 3) << 3) | (((s >> 4) & 1) << 2);
}
// explicit drain of outstanding global_load_lds before a barrier
static __device__ __forceinline__ void vm_drain() {
  asm volatile("s_waitcnt vmcnt(0)" ::: "memory");
}

template <bool FP32>
static __device__ __forceinline__ float load1(const void* p, size_t i) {
  if (FP32) return ((const float*)p)[i];
  else      return bf2f(((const unsigned short*)p)[i]);
}
template <bool FP32>
static __device__ __forceinline__ bf16x8 load8bf(const void* p, size_t i) {
  if (FP32) {
    f32x4 a = *(const f32x4*)((const float*)p + i);
    f32x4 b = *(const f32x4*)((const float*)p + i + 4);
    union { bf16x8 v; unsigned short u[8]; } r;
#pragma unroll
    for (int j = 0; j < 4; ++j) { r.u[j] = f2bf(a[j]); r.u[4 + j] = f2bf(b[j]); }
    return r.v;
  } else {
    return *(const bf16x8*)((const unsigned short*)p + i);
  }
}
static __device__ __forceinline__ bf16x8 load8bf_rt(const void* p, size_t i, bool fp32) {
  return fp32 ? load8bf<true>(p, i) : load8bf<false>(p, i);
}

// async global->LDS, 16B/lane; per-lane LDS dest = wave-uniform base + lane*16
static __device__ __forceinline__ void glds16(const unsigned short* g, unsigned short* l) {
  __builtin_amdgcn_global_load_lds(
      (const __attribute__((address_space(1))) unsigned int*)(unsigned long long)(const void*)g,
      (__attribute__((address_space(3))) unsigned int*)(unsigned int)(unsigned long long)(void*)l,
      16, 0, 0);
}

// ---------------- dtype detector (1024 threads, 4096 samples) ----------------
__global__ void detect_dtype(const unsigned short* __restrict__ X, int* __restrict__ flag) {
  __shared__ int zc[1024], bc[1024];
  int z = 0, b = 0;
  for (int i = threadIdx.x; i < 4096; i += 1024) {
    unsigned short u = X[8 * i];          // stride samples across the buffer
    if (u == 0) z++;
    int e = (u >> 7) & 0xff;
    if (e >= 134) b++;
  }
  zc[threadIdx.x] = z; bc[threadIdx.x] = b;
  __syncthreads();
  for (int s = 512; s > 0; s >>= 1) {
    if (threadIdx.x < s) { zc[threadIdx.x] += zc[threadIdx.x + s]; bc[threadIdx.x] += bc[threadIdx.x + s]; }
    __syncthreads();
  }
  if (threadIdx.x == 0)
    *flag = (zc[0] > 2048 || bc[0] > 16) ? 1 : 0;   // 1 = fp32 buffers
}

// ---------------- convert inputs to bf16 (+ fp32 bias), unified ------------
__global__ void convert_all_u(const void* __restrict__ X,
                              const void* __restrict__ Wq, const void* __restrict__ Wk,
                              const void* __restrict__ Wv,
                              const void* __restrict__ bq, const void* __restrict__ bk,
                              const void* __restrict__ bv,
                              unsigned char* __restrict__ ws, const int* __restrict__ flag) {
  const bool fp32 = (*flag != 0);
  unsigned short* Xb = (unsigned short*)(ws + WS_XBF);
  unsigned short* Wb = (unsigned short*)(ws + WS_WBF);
  float* Bb = (float*)(ws + WS_BF32);
  int blk = blockIdx.x;
  if (blk < 4096) {
    size_t base = ((size_t)blk * 256 + threadIdx.x) * 8;
    *(bf16x8*)(Xb + base) = load8bf_rt(X, base, fp32);
  } else if (blk < 5632) {
    int w = (blk - 4096) >> 9;
    int r = (blk - 4096) & 511;
    const void* W = (w == 0) ? Wq : (w == 1) ? Wk : Wv;
    size_t base = ((size_t)r * 256 + threadIdx.x) * 8;
    *(bf16x8*)(Wb + (size_t)w * 1048576 + base) = load8bf_rt(W, base, fp32);
  } else {
    int w = blk - 5632;
    const void* Bsrc = (w == 0) ? bq : (w == 1) ? bk : bv;
    for (int i = threadIdx.x; i < 1024; i += 256)
      Bb[w * 1024 + i] = fp32 ? load1<true>(Bsrc, i) : load1<false>(Bsrc, i);
  }
}

// ---------------- QKV projection GEMM (bf16, 8-wave dbuf glds16) ------------
// 128x128 tile, BK=64, 512 threads (8 waves: wave tile 64x32, acc 4x2).
// LDS 2x(Xs16K+Ws16K)=64KB double-buffered; 16B seg phys = logical ^ (row&7),
// staged via glds16 with pre-swizzled global source. Prefetch before compute.
// Explicit vmcnt(0) drain before each barrier (R10 hardening).
// z<2: MFMA(A=W, B=X) -> lane col walks s, reg r walks hd -> 8-B Q/K stores.
// z=2: MFMA(A=X, B=W) -> reg r walks s -> 8-B packed V stores (key-swizzled).
__global__ __launch_bounds__(512, 2) void qkv_bf(
    const unsigned short* __restrict__ Xb, const unsigned short* __restrict__ Wb,
    const float* __restrict__ Bb,
    unsigned short* __restrict__ Qo, unsigned short* __restrict__ Ko,
    unsigned short* __restrict__ Vo)
{
  // XCD swizzle: nwg=1536, 8 XCDs, 192 blocks/XCD chunk
  const int bid = blockIdx.x;
  const int wg  = (bid & 7) * 192 + (bid >> 3);
  const int z   = wg / 512;          // 0..2 (matrix)
  const int rem = wg - z * 512;
  const int nb  = rem >> 6;          // 0..7  (W-panel; 64 consecutive wg share it)
  const int mb  = rem & 63;          // 0..63
  const unsigned short* W = Wb + (size_t)z * 1048576;

  __shared__ __align__(16) unsigned short Xs[2][128 * 64];
  __shared__ __align__(16) unsigned short Ws[2][128 * 64];

  const int tid  = threadIdx.x;
  const int wave = tid >> 6;        // 0..7
  const int lane = tid & 63;
  const int col  = lane & 15;
  const int quad = lane >> 4;
  const int wr = wave & 1;          // m half (64 rows)
  const int wc = wave >> 1;         // n quarter (32 cols)
  const int m0 = mb * 128;
  const int n0 = nb * 128;

  f32x4 zero4 = {0.f, 0.f, 0.f, 0.f};
  f32x4 acc[4][2];
#pragma unroll
  for (int i = 0; i < 4; ++i)
#pragma unroll
    for (int j = 0; j < 2; ++j) acc[i][j] = zero4;

  // staging: per buf, X/W are 128 rows x 128B. Per glds16 call (512 lanes)
  // covers 64 rows; wave covers rows [a*64 + wave*8, +8).
  const int srow8 = lane >> 3;   // 0..7: row within 8-row wave group
  const int sseg  = lane & 7;    // phys 16B seg within 128B row
  const int lseg  = sseg ^ srow8;  // row&7 == srow8 (bases are mult of 8)
  const unsigned short* xA0 = Xb + (size_t)(m0 + 0  + wave * 8 + srow8) * DIM + lseg * 8;
  const unsigned short* xA1 = Xb + (size_t)(m0 + 64 + wave * 8 + srow8) * DIM + lseg * 8;
  const unsigned short* wA0 = W  + (size_t)(n0 + 0  + wave * 8 + srow8) * DIM + lseg * 8;
  const unsigned short* wA1 = W  + (size_t)(n0 + 64 + wave * 8 + srow8) * DIM + lseg * 8;

  auto stage = [&](int k0, int bufn) {
    unsigned short* Xd = Xs[bufn] + (wave * 8) * 64;
    unsigned short* Wd = Ws[bufn] + (wave * 8) * 64;
    glds16(xA0 + k0, Xd);
    glds16(xA1 + k0, Xd + 64 * 64);
    glds16(wA0 + k0, Wd);
    glds16(wA1 + k0, Wd + 64 * 64);
  };

  stage(0, 0);   // prologue prefetch

  if (z < 2) {
    // ---- Q/K: swapped operands (A=W frag, B=X frag) ----
    for (int ks = 0; ks < 16; ++ks) {
      vm_drain();                 // own in-flight glds16 landed
      __syncthreads();            // all waves' glds16 landed -> buf[ks&1] ready
      if (ks < 15) stage((ks + 1) * 64, (ks + 1) & 1);
      const unsigned short* Xc = Xs[ks & 1];
      const unsigned short* Wc = Ws[ks & 1];
#pragma unroll
      for (int kk = 0; kk < 2; ++kk) {
        bf16x8 Af[4], Bf[2];
#pragma unroll
        for (int i = 0; i < 4; ++i) {
          int ra = wr * 64 + i * 16 + col;
          Af[i] = *(const bf16x8*)(Xc + ra * 64 + ((kk * 4 + quad) ^ (ra & 7)) * 8);
        }
#pragma unroll
        for (int j = 0; j < 2; ++j) {
          int rb = wc * 32 + j * 16 + col;
          Bf[j] = *(const bf16x8*)(Wc + rb * 64 + ((kk * 4 + quad) ^ (rb & 7)) * 8);
        }
#pragma unroll
        for (int i = 0; i < 4; ++i)
#pragma unroll
          for (int j = 0; j < 2; ++j)
            acc[i][j] = __builtin_amdgcn_mfma_f32_16x16x32_bf16(Bf[j], Af[i], acc[i][j], 0, 0, 0);
      }
    }

    // epilogue: lane col -> s (within 16), reg r -> hd. 8-B packed stores.
    const float oscale = (z == 0) ? QSCALE : 1.0f;
    unsigned short* Yo = (z == 0) ? Qo : Ko;
#pragma unroll
    for (int i = 0; i < 4; ++i) {
      int m = m0 + wr * 64 + i * 16 + col;
      int b = m >> 11, s = m & 2047;
#pragma unroll
      for (int j = 0; j < 2; ++j) {
        int n = n0 + wc * 32 + j * 16 + quad * 4;    // hd base (4-aligned)
        f32x4 bv4 = *(const f32x4*)(Bb + z * 1024 + n);
        int h = n >> 6, hd = n & 63;
        unsigned lo = cvtpk((acc[i][j][0] + bv4[0]) * oscale,
                            (acc[i][j][1] + bv4[1]) * oscale);
        unsigned hi = cvtpk((acc[i][j][2] + bv4[2]) * oscale,
                            (acc[i][j][3] + bv4[3]) * oscale);
        unsigned long long pk = (unsigned long long)lo | ((unsigned long long)hi << 32);
        *(unsigned long long*)(Yo + ((size_t)(b * NH + h) * SEQ + s) * HDIM + hd) = pk;
      }
    }
  } else {
    // ---- V: original orientation (A=X frag, B=W frag) ----
    for (int ks = 0; ks < 16; ++ks) {
      vm_drain();
      __syncthreads();
      if (ks < 15) stage((ks + 1) * 64, (ks + 1) & 1);
      const unsigned short* Xc = Xs[ks & 1];
      const unsigned short* Wc = Ws[ks & 1];
#pragma unroll
      for (int kk = 0; kk < 2; ++kk) {
        bf16x8 Af[4], Bf[2];
#pragma unroll
        for (int i = 0; i < 4; ++i) {
          int ra = wr * 64 + i * 16 + col;
          Af[i] = *(const bf16x8*)(Xc + ra * 64 + ((kk * 4 + quad) ^ (ra & 7)) * 8);
        }
#pragma unroll
        for (int j = 0; j < 2; ++j) {
          int rb = wc * 32 + j * 16 + col;
          Bf[j] = *(const bf16x8*)(Wc + rb * 64 + ((kk * 4 + quad) ^ (rb & 7)) * 8);
        }
#pragma unroll
        for (int i = 0; i < 4; ++i)
#pragma unroll
          for (int j = 0; j < 2; ++j)
            acc[i][j] = __builtin_amdgcn_mfma_f32_16x16x32_bf16(Af[i], Bf[j], acc[i][j], 0, 0, 0);
      }
    }

    // V epilogue: transposed [bh][hd][SEQ], KEY-SWIZZLED (4-key chunk -> vswz)
#pragma unroll
    for (int i = 0; i < 4; ++i) {
#pragma unroll
      for (int j = 0; j < 2; ++j) {
        int n = n0 + wc * 32 + j * 16 + col;
        float bvf = Bb[2 * 1024 + n];
        int h = n >> 6, hd = n & 63;
        int mbase = m0 + wr * 64 + i * 16 + quad * 4;
        int b = mbase >> 11, s = mbase & 2047;
        unsigned lo = cvtpk(acc[i][j][0] + bvf, acc[i][j][1] + bvf);
        unsigned hi = cvtpk(acc[i][j][2] + bvf, acc[i][j][3] + bvf);
        unsigned long long pk = (unsigned long long)lo | ((unsigned long long)hi << 32);
        *(unsigned long long*)(Vo + ((size_t)(b * NH + h) * HDIM + hd) * SEQ + vswz(s)) = pk;
      }
    }
  }
}

// ---------------- fallback QKV (raw inputs, flag-gated) ----------------
#define XS_STRIDE 40
template <bool FP32>
__global__ __launch_bounds__(256) void qkv_any(
    const void* __restrict__ X,
    const void* __restrict__ Wq, const void* __restrict__ bq,
    const void* __restrict__ Wk, const void* __restrict__ bk,
    const void* __restrict__ Wv, const void* __restrict__ bv,
    unsigned short* __restrict__ Qo, unsigned short* __restrict__ Ko,
    unsigned short* __restrict__ Vo, const int* __restrict__ flag)
{
  if (*flag != (FP32 ? 1 : 0)) return;
  const int z = blockIdx.z;
  const void* W    = (z == 0) ? Wq : (z == 1) ? Wk : Wv;
  const void* bias = (z == 0) ? bq : (z == 1) ? bk : bv;

  __shared__ __align__(16) unsigned short Xs[128 * XS_STRIDE];
  __shared__ __align__(16) unsigned short Ws[128 * XS_STRIDE];

  const int tid  = threadIdx.x;
  const int wave = tid >> 6;
  const int lane = tid & 63;
  const int col  = lane & 15;
  const int quad = lane >> 4;
  const int wr = wave & 1;
  const int wc = wave >> 1;
  const int m0 = blockIdx.x * 128;
  const int n0 = blockIdx.y * 128;

  f32x4 zero4 = {0.f, 0.f, 0.f, 0.f};
  f32x4 acc[4][4];
#pragma unroll
  for (int i = 0; i < 4; ++i)
#pragma unroll
    for (int j = 0; j < 4; ++j) acc[i][j] = zero4;

  const int srow = tid >> 2;
  const int sseg = (tid & 3) << 3;

  for (int k0 = 0; k0 < DIM; k0 += 32) {
    __syncthreads();
#pragma unroll
    for (int a = 0; a < 2; ++a) {
      int r = a * 64 + srow;
      *(bf16x8*)(Xs + r * XS_STRIDE + sseg) = load8bf<FP32>(X, (size_t)(m0 + r) * DIM + k0 + sseg);
      *(bf16x8*)(Ws + r * XS_STRIDE + sseg) = load8bf<FP32>(W, (size_t)(n0 + r) * DIM + k0 + sseg);
    }
    __syncthreads();

    bf16x8 Af[4], Bf[4];
#pragma unroll
    for (int i = 0; i < 4; ++i)
      Af[i] = *(const bf16x8*)(Xs + (wr * 64 + i * 16 + col) * XS_STRIDE + quad * 8);
#pragma unroll
    for (int j = 0; j < 4; ++j)
      Bf[j] = *(const bf16x8*)(Ws + (wc * 64 + j * 16 + col) * XS_STRIDE + quad * 8);
#pragma unroll
    for (int i = 0; i < 4; ++i)
#pragma unroll
      for (int j = 0; j < 4; ++j)
        acc[i][j] = __builtin_amdgcn_mfma_f32_16x16x32_bf16(Af[i], Bf[j], acc[i][j], 0, 0, 0);
  }

  const float oscale = (z == 0) ? QSCALE : 1.0f;
  if (z < 2) {
    unsigned short* Yo = (z == 0) ? Qo : Ko;
#pragma unroll
    for (int i = 0; i < 4; ++i) {
#pragma unroll
      for (int j = 0; j < 4; ++j) {
        int n = n0 + wc * 64 + j * 16 + col;
        float bvf = load1<FP32>(bias, n);
        int h = n >> 6, hd = n & 63;
#pragma unroll
        for (int r = 0; r < 4; ++r) {
          int m = m0 + wr * 64 + i * 16 + quad * 4 + r;
          int b = m >> 11, s = m & 2047;
          Yo[((size_t)(b * NH + h) * SEQ + s) * HDIM + hd] = f2bf((acc[i][j][r] + bvf) * oscale);
        }
      }
    }
  } else {
#pragma unroll
    for (int i = 0; i < 4; ++i) {
#pragma unroll
      for (int j = 0; j < 4; ++j) {
        int n = n0 + wc * 64 + j * 16 + col;
        float bvf = load1<FP32>(bias, n);
        int h = n >> 6, hd = n & 63;
        int mbase = m0 + wr * 64 + i * 16 + quad * 4;
        int b = mbase >> 11, s = mbase & 2047;
        unsigned long long pk = 0;
#pragma unroll
        for (int r = 0; r < 4; ++r)
          pk |= (unsigned long long)f2bf(acc[i][j][r] + bvf) << (16 * r);
        *(unsigned long long*)(Vo + ((size_t)(b * NH + h) * HDIM + hd) * SEQ + vswz(s)) = pk;
      }
    }
  }
}

// ---------------- flash attention (single launch, runtime fp32) -----------
// grid (8, 64), block 512 (8 waves); wave = 32 queries (2 column groups
// sharing K/V fragment reads). 256 queries/block. Scores transposed (S^T).
// K LDS: 2 x [128 rows x 128B], 16B seg phys = logical ^ (row&7)  (glds16)
// V LDS: 2 x [64 rows x 256B] (keys pre-swizzled in ws), seg phys = logical ^ (row&15)
// Double-buffered: prefetch kt+1 issued before compute on kt; explicit
// vmcnt(0) drain + barrier guarantees buf[kt&1] ready (R10 hardening).
// Bv fragments for tp=0,1 hoisted before softmax (latency hidden under VALU).
__global__ __launch_bounds__(512, 2) void attn_kernel(
    const unsigned short* __restrict__ Q,
    const unsigned short* __restrict__ K,
    const unsigned short* __restrict__ Vt,   // [bh][hd][SEQ], key-swizzled
    const void* __restrict__ mask,
    void* __restrict__ OutV, const int* __restrict__ flag)
{
  const bool fp32 = (*flag != 0);

  __shared__ __align__(16) unsigned short Ks[2 * 128 * 64];
  __shared__ __align__(16) unsigned short Vs[2 * 64 * 128];
  __shared__ __align__(16) float Msall[SEQ];

  const int tid  = threadIdx.x;
  const int wave = tid >> 6;        // 0..7
  const int lane = tid & 63;
  const int col  = lane & 15;
  const int quad = lane >> 4;
  const int qt = blockIdx.x;        // 0..7
  const int bh = blockIdx.y;
  const int b  = bh >> 4;
  const int h  = bh & 15;

  const unsigned short* Qb = Q  + (size_t)bh * SEQ * HDIM;
  const unsigned short* Kb = K  + (size_t)bh * SEQ * HDIM;
  const unsigned short* Vb = Vt + (size_t)bh * HDIM * SEQ;

  // ---- stage mask row once (pre-multiplied by LOG2E); 4 floats/thread ----
  {
    if (fp32) {
      f32x4 a = *(const f32x4*)((const float*)mask + (size_t)b * SEQ + tid * 4);
#pragma unroll
      for (int j = 0; j < 4; ++j) a[j] *= LOG2E;
      *(f32x4*)(Msall + tid * 4) = a;
    } else {
      bf16x4 v = *(const bf16x4*)((const unsigned short*)mask + (size_t)b * SEQ + tid * 4);
      f32x4 a;
#pragma unroll
      for (int j = 0; j < 4; ++j) a[j] = bf2f((unsigned short)v[j]) * LOG2E;
      *(f32x4*)(Msall + tid * 4) = a;
    }
  }

  // ---- Q fragments: two 16-query groups per wave ----
  const int qrow0 = qt * 256 + wave * 32 + col;
  const int qrow1 = qrow0 + 16;
  const bf16x8 Qf00 = *(const bf16x8*)(Qb + (size_t)qrow0 * HDIM + quad * 8);
  const bf16x8 Qf01 = *(const bf16x8*)(Qb + (size_t)qrow0 * HDIM + 32 + quad * 8);
  const bf16x8 Qf10 = *(const bf16x8*)(Qb + (size_t)qrow1 * HDIM + quad * 8);
  const bf16x8 Qf11 = *(const bf16x8*)(Qb + (size_t)qrow1 * HDIM + 32 + quad * 8);

  const f32x4 z4 = {0.f, 0.f, 0.f, 0.f};
  f32x4 Oacc0[4], Oacc1[4];
  f32x4 Osum0 = z4, Osum1 = z4;
#pragma unroll
  for (int t = 0; t < 4; ++t) { Oacc0[t] = z4; Oacc1[t] = z4; }
  float mrun0 = -1e30f, mrun1 = -1e30f;

  union { bf16x8 v; unsigned u[4]; } ones;
#pragma unroll
  for (int i = 0; i < 4; ++i) ones.u[i] = 0x3F803F80u;   // bf16 1.0 x2

  // ---- loop-invariant staging addresses ----
  const int krow_in = lane >> 3;            // 0..7
  const int kphys   = lane & 7;             // 16B seg within 128B row
  const int klseg   = kphys ^ krow_in;      // loop/a-invariant
  const unsigned short* kSrc0 = Kb + (size_t)(wave * 16 + 0 + krow_in) * HDIM + klseg * 8;
  const unsigned short* kSrc1 = Kb + (size_t)(wave * 16 + 8 + krow_in) * HDIM + klseg * 8;
  const int vrow_in = lane >> 4;            // 0..3
  const int vphys   = lane & 15;            // 16B seg within 256B row
  const int vrowA0  = wave * 8 + 0 + vrow_in;
  const int vrowA1  = wave * 8 + 4 + vrow_in;
  const unsigned short* vSrc0 = Vb + (size_t)vrowA0 * SEQ + (vphys ^ (vrowA0 & 15)) * 8;
  const unsigned short* vSrc1 = Vb + (size_t)vrowA1 * SEQ + (vphys ^ (vrowA1 & 15)) * 8;

  auto stage = [&](int ktn, int bufn) {
    unsigned short* Kdst = Ks + bufn * (128 * 64) + (wave * 16) * 64;
    unsigned short* Vdst = Vs + bufn * (64 * 128) + (wave * 8) * 128;
    const size_t ko = (size_t)ktn * 128 * HDIM;
    const size_t vo = (size_t)ktn * 128;
    glds16(kSrc0 + ko, Kdst);
    glds16(kSrc1 + ko, Kdst + 8 * 64);
    glds16(vSrc0 + vo, Vdst);
    glds16(vSrc1 + vo, Vdst + 4 * 128);
  };

  stage(0, 0);   // prologue prefetch

  for (int kt = 0; kt < 16; ++kt) {
    vm_drain();                             // own in-flight glds16 landed
    __syncthreads();                        // all waves' -> buf[kt&1] ready
    if (kt < 15) stage(kt + 1, (kt + 1) & 1);

    const unsigned short* Kcur = Ks + (kt & 1) * (128 * 64);
    const unsigned short* Vcur = Vs + (kt & 1) * (64 * 128);
    const float* Mc = Msall + kt * 128;

    // --- QK^T (S^T, log2 domain): C initialized with mask; K frags shared ---
    f32x4 st0[8], st1[8];
    __builtin_amdgcn_s_setprio(1);
#pragma unroll
    for (int t = 0; t < 8; ++t) {
      const unsigned short* kr = Kcur + (t * 16 + col) * 64;
      bf16x8 Ka = *(const bf16x8*)(kr + (quad ^ (col & 7)) * 8);
      bf16x8 Kc = *(const bf16x8*)(kr + ((4 + quad) ^ (col & 7)) * 8);
      f32x4 c = *(const f32x4*)(Mc + t * 16 + quad * 4);   // mask*log2e as C
      f32x4 d0 = c, d1 = c;
      d0 = __builtin_amdgcn_mfma_f32_16x16x32_bf16(Ka, Qf00, d0, 0, 0, 0);
      d0 = __builtin_amdgcn_mfma_f32_16x16x32_bf16(Kc, Qf01, d0, 0, 0, 0);
      d1 = __builtin_amdgcn_mfma_f32_16x16x32_bf16(Ka, Qf10, d1, 0, 0, 0);
      d1 = __builtin_amdgcn_mfma_f32_16x16x32_bf16(Kc, Qf11, d1, 0, 0, 0);
      st0[t] = d0; st1[t] = d1;
    }
    __builtin_amdgcn_s_setprio(0);

    // --- hoisted V fragments for tp=0,1: ds_reads complete under softmax ---
    bf16x8 Bv01[2][4];
#pragma unroll
    for (int tp = 0; tp < 2; ++tp)
#pragma unroll
      for (int t2 = 0; t2 < 4; ++t2)
        Bv01[tp][t2] = *(const bf16x8*)(Vcur + (t2 * 16 + col) * 128 + ((tp * 4 + quad) ^ col) * 8);

    // --- online softmax (per query = col; keys in-lane), defer-max ---
    float pm0, pm1;
    {
      f32x4 m40, m41;
#pragma unroll
      for (int r = 0; r < 4; ++r) {
        float a0 = fmaxf(fmaxf(st0[0][r], st0[1][r]), st0[2][r]);
        a0 = fmaxf(fmaxf(a0, st0[3][r]), st0[4][r]);
        a0 = fmaxf(fmaxf(a0, st0[5][r]), st0[6][r]);
        m40[r] = fmaxf(a0, st0[7][r]);
        float a1 = fmaxf(fmaxf(st1[0][r], st1[1][r]), st1[2][r]);
        a1 = fmaxf(fmaxf(a1, st1[3][r]), st1[4][r]);
        a1 = fmaxf(fmaxf(a1, st1[5][r]), st1[6][r]);
        m41[r] = fmaxf(a1, st1[7][r]);
      }
      pm0 = fmaxf(fmaxf(fmaxf(m40[0], m40[1]), m40[2]), m40[3]);
      pm1 = fmaxf(fmaxf(fmaxf(m41[0], m41[1]), m41[2]), m41[3]);
    }
    pm0 = fmaxf(pm0, __shfl_xor(pm0, 16, 64));
    pm0 = fmaxf(pm0, __shfl_xor(pm0, 32, 64));
    pm1 = fmaxf(pm1, __shfl_xor(pm1, 16, 64));
    pm1 = fmaxf(pm1, __shfl_xor(pm1, 32, 64));

    if (!__all((pm0 - mrun0 <= 8.0f) && (pm1 - mrun1 <= 8.0f))) {
      float mn0 = fmaxf(mrun0, pm0), mn1 = fmaxf(mrun1, pm1);
      float a0 = __builtin_amdgcn_exp2f(mrun0 - mn0);
      float a1 = __builtin_amdgcn_exp2f(mrun1 - mn1);
      mrun0 = mn0; mrun1 = mn1;
      float av0[4], av1[4];
#pragma unroll
      for (int r = 0; r < 4; ++r) {
        av0[r] = __shfl(a0, quad * 4 + r, 64);
        av1[r] = __shfl(a1, quad * 4 + r, 64);
      }
#pragma unroll
      for (int t = 0; t < 4; ++t)
#pragma unroll
        for (int r = 0; r < 4; ++r) {
          Oacc0[t][r] *= av0[r];
          Oacc1[t][r] *= av1[r];
        }
#pragma unroll
      for (int r = 0; r < 4; ++r) { Osum0[r] *= av0[r]; Osum1[r] *= av1[r]; }
    }

#pragma unroll
    for (int t = 0; t < 8; ++t)
#pragma unroll
      for (int r = 0; r < 4; ++r) {
        st0[t][r] = __builtin_amdgcn_exp2f(st0[t][r] - mrun0);
        st1[t][r] = __builtin_amdgcn_exp2f(st1[t][r] - mrun1);
      }

    // --- PV + row-sum via MFMA; P straight from score regs; V frags shared ---
    __builtin_amdgcn_s_setprio(1);
#pragma unroll
    for (int tp = 0; tp < 4; ++tp) {
      union { bf16x8 v; unsigned u[4]; } A0, A1;
      A0.u[0] = cvtpk(st0[2 * tp][0],     st0[2 * tp][1]);
      A0.u[1] = cvtpk(st0[2 * tp][2],     st0[2 * tp][3]);
      A0.u[2] = cvtpk(st0[2 * tp + 1][0], st0[2 * tp + 1][1]);
      A0.u[3] = cvtpk(st0[2 * tp + 1][2], st0[2 * tp + 1][3]);
      A1.u[0] = cvtpk(st1[2 * tp][0],     st1[2 * tp][1]);
      A1.u[1] = cvtpk(st1[2 * tp][2],     st1[2 * tp][3]);
      A1.u[2] = cvtpk(st1[2 * tp + 1][0], st1[2 * tp + 1][1]);
      A1.u[3] = cvtpk(st1[2 * tp + 1][2], st1[2 * tp + 1][3]);
      Osum0 = __builtin_amdgcn_mfma_f32_16x16x32_bf16(A0.v, ones.v, Osum0, 0, 0, 0);
      Osum1 = __builtin_amdgcn_mfma_f32_16x16x32_bf16(A1.v, ones.v, Osum1, 0, 0, 0);
#pragma unroll
      for (int t2 = 0; t2 < 4; ++t2) {
        bf16x8 Bv = (tp < 2) ? Bv01[tp][t2]
                  : *(const bf16x8*)(Vcur + (t2 * 16 + col) * 128 + ((tp * 4 + quad) ^ col) * 8);
        Oacc0[t2] = __builtin_amdgcn_mfma_f32_16x16x32_bf16(A0.v, Bv, Oacc0[t2], 0, 0, 0);
        Oacc1[t2] = __builtin_amdgcn_mfma_f32_16x16x32_bf16(A1.v, Bv, Oacc1[t2], 0, 0, 0);
      }
    }
    __builtin_amdgcn_s_setprio(0);
  }

  // epilogue: rows q = quad*4+r within each 16-query group; l sits in Osum rows
  float liv0[4], liv1[4];
#pragma unroll
  for (int r = 0; r < 4; ++r) { liv0[r] = 1.0f / Osum0[r]; liv1[r] = 1.0f / Osum1[r]; }
#pragma unroll
  for (int t2 = 0; t2 < 4; ++t2) {
#pragma unroll
    for (int r = 0; r < 4; ++r) {
      int q0 = qt * 256 + wave * 32 + quad * 4 + r;
      int q1 = q0 + 16;
      float v0 = Oacc0[t2][r] * liv0[r];
      float v1 = Oacc1[t2][r] * liv1[r];
      v0 = (v0 == v0) ? v0 : 0.0f;
      v1 = (v1 == v1) ? v1 : 0.0f;
      size_t o0 = ((size_t)b * SEQ + q0) * DIM + h * HDIM + t2 * 16 + col;
      size_t o1 = ((size_t)b * SEQ + q1) * DIM + h * HDIM + t2 * 16 + col;
      if (fp32) {
        ((float*)OutV)[o0] = v0;
        ((float*)OutV)[o1] = v1;
      } else {
        ((unsigned short*)OutV)[o0] = f2bf(v0);
        ((unsigned short*)OutV)[o1] = f2bf(v1);
      }
    }
  }
}

extern "C" void kernel_launch(void* const* d_in, const int* in_sizes, int n_in,
                              void* d_out, int out_size, void* d_ws, size_t ws_size,
                              hipStream_t stream) {
  const void* X    = d_in[0];
  const void* mask = d_in[1];
  const void* Wq   = d_in[2];
  const void* bq   = d_in[3];
  const void* Wk   = d_in[4];
  const void* bk   = d_in[5];
  const void* Wv   = d_in[6];
  const void* bv   = d_in[7];

  unsigned char* ws = (unsigned char*)d_ws;
  unsigned short* Qw = (unsigned short*)ws;
  unsigned short* Kw = Qw + QKV_ELEMS;
  unsigned short* Vw = Kw + QKV_ELEMS;
  int* flag = (int*)(ws + WS_FLAG);

  detect_dtype<<<1, 1024, 0, stream>>>((const unsigned short*)X, flag);

  if (ws_size >= WS_NEED) {
    convert_all_u<<<5635, 256, 0, stream>>>(X, Wq, Wk, Wv, bq, bk, bv, ws, flag);
    qkv_bf<<<1536, 512, 0, stream>>>(
        (const unsigned short*)(ws + WS_XBF), (const unsigned short*)(ws + WS_WBF),
        (const float*)(ws + WS_BF32), Qw, Kw, Vw);
  } else {
    qkv_any<false><<<dim3(64, 8, 3), 256, 0, stream>>>(X, Wq, bq, Wk, bk, Wv, bv, Qw, Kw, Vw, flag);
    qkv_any<true ><<<dim3(64, 8, 3), 256, 0, stream>>>(X, Wq, bq, Wk, bk, Wv, bv, Qw, Kw, Vw, flag);
  }

  attn_kernel<<<dim3(8, 64), 512, 0, stream>>>(Qw, Kw, Vw, mask, d_out, flag);
}

// Round 11
// 251.849 us; speedup vs baseline: 1.0323x; 1.0323x over previous
//
#include <hip/hip_runtime.h>

// BertSelfAttention: B=4 S=2048 D=1024 H=16 HD=64. Input buffers fp32 (runtime
// detected; bf16 fallback). detect -> convert to bf16 in ws -> qkv GEMM
// (128Mx256N tile, BK=32, 512-thr 8-wave, dbuf glds16, XOR-seg swizzle,
// XCD-chunked, EXPLICIT vmcnt(0) drain before every in-loop barrier) ->
// flash attention (single launch, runtime fp32 flag):
//   - 512-thread blocks (8 waves), 256 queries/block, 32 queries/wave
//   - __launch_bounds__(512, 2); dbuf K/V LDS with drain+barrier
//   - ALL 16 Bv fragments hoisted before softmax (PV loop is LDS-free)
//   - mask staged once; defer-max rescale; cvt_pk packing; setprio
// HISTORY: R7 ran this qkv tile shape WITHOUT the explicit drain -> replay-
// corruption (stale-LDS race signature). R10 verified the explicit drain is
// zero-cost. This round retries the faster tile WITH the drain: pre-committed
// read = PASS confirms the barrier-drain race theory; FAIL kills the family
// (revert to the R10 file, which is fully verified at 258-260us).

typedef short bf16x4 __attribute__((ext_vector_type(4)));
typedef short bf16x8 __attribute__((ext_vector_type(8)));
typedef float f32x4 __attribute__((ext_vector_type(4)));

#define SEQ 2048
#define DIM 1024
#define NH 16
#define HDIM 64
#define QKV_ELEMS ((size_t)64 * SEQ * HDIM)

#define WS_FLAG  50331648ull
#define WS_XBF   50331904ull
#define WS_WBF   67109120ull
#define WS_BF32  73400576ull
#define WS_NEED  73412868ull

#define LOG2E 1.4426950408889634f
#define QSCALE (0.125f * LOG2E)

static __device__ __forceinline__ unsigned short f2bf(float f) {
  union { float f; unsigned u; } x; x.f = f;
  unsigned r = x.u + 0x7fffu + ((x.u >> 16) & 1u);
  return (unsigned short)(r >> 16);
}
static __device__ __forceinline__ float bf2f(unsigned short h) {
  union { unsigned u; float f; } x; x.u = ((unsigned)h) << 16;
  return x.f;
}
// packed f32x2 -> bf16x2 (lo=a, hi=b), single HW instr
static __device__ __forceinline__ unsigned cvtpk(float a, float b) {
  unsigned r;
  asm("v_cvt_pk_bf16_f32 %0, %1, %2" : "=v"(r) : "v"(a), "v"(b));
  return r;
}
// V key-swizzle for an aligned 4-key chunk base (s % 4 == 0)
static __device__ __forceinline__ int vswz(int s) {
  return (s & ~31) | (((s >> 2) & 3) << 3) | (((s >> 4) & 1) << 2);
}
// explicit drain of outstanding global_load_lds before a barrier
static __device__ __forceinline__ void vm_drain() {
  asm volatile("s_waitcnt vmcnt(0)" ::: "memory");
}

template <bool FP32>
static __device__ __forceinline__ float load1(const void* p, size_t i) {
  if (FP32) return ((const float*)p)[i];
  else      return bf2f(((const unsigned short*)p)[i]);
}
template <bool FP32>
static __device__ __forceinline__ bf16x8 load8bf(const void* p, size_t i) {
  if (FP32) {
    f32x4 a = *(const f32x4*)((const float*)p + i);
    f32x4 b = *(const f32x4*)((const float*)p + i + 4);
    union { bf16x8 v; unsigned short u[8]; } r;
#pragma unroll
    for (int j = 0; j < 4; ++j) { r.u[j] = f2bf(a[j]); r.u[4 + j] = f2bf(b[j]); }
    return r.v;
  } else {
    return *(const bf16x8*)((const unsigned short*)p + i);
  }
}
static __device__ __forceinline__ bf16x8 load8bf_rt(const void* p, size_t i, bool fp32) {
  return fp32 ? load8bf<true>(p, i) : load8bf<false>(p, i);
}

// async global->LDS, 16B/lane; per-lane LDS dest = wave-uniform base + lane*16
static __device__ __forceinline__ void glds16(const unsigned short* g, unsigned short* l) {
  __builtin_amdgcn_global_load_lds(
      (const __attribute__((address_space(1))) unsigned int*)(unsigned long long)(const void*)g,
      (__attribute__((address_space(3))) unsigned int*)(unsigned int)(unsigned long long)(void*)l,
      16, 0, 0);
}

// ---------------- dtype detector (1024 threads, 4096 samples) ----------------
__global__ void detect_dtype(const unsigned short* __restrict__ X, int* __restrict__ flag) {
  __shared__ int zc[1024], bc[1024];
  int z = 0, b = 0;
  for (int i = threadIdx.x; i < 4096; i += 1024) {
    unsigned short u = X[8 * i];          // stride samples across the buffer
    if (u == 0) z++;
    int e = (u >> 7) & 0xff;
    if (e >= 134) b++;
  }
  zc[threadIdx.x] = z; bc[threadIdx.x] = b;
  __syncthreads();
  for (int s = 512; s > 0; s >>= 1) {
    if (threadIdx.x < s) { zc[threadIdx.x] += zc[threadIdx.x + s]; bc[threadIdx.x] += bc[threadIdx.x + s]; }
    __syncthreads();
  }
  if (threadIdx.x == 0)
    *flag = (zc[0] > 2048 || bc[0] > 16) ? 1 : 0;   // 1 = fp32 buffers
}

// ---------------- convert inputs to bf16 (+ fp32 bias), unified ------------
__global__ void convert_all_u(const void* __restrict__ X,
                              const void* __restrict__ Wq, const void* __restrict__ Wk,
                              const void* __restrict__ Wv,
                              const void* __restrict__ bq, const void* __restrict__ bk,
                              const void* __restrict__ bv,
                              unsigned char* __restrict__ ws, const int* __restrict__ flag) {
  const bool fp32 = (*flag != 0);
  unsigned short* Xb = (unsigned short*)(ws + WS_XBF);
  unsigned short* Wb = (unsigned short*)(ws + WS_WBF);
  float* Bb = (float*)(ws + WS_BF32);
  int blk = blockIdx.x;
  if (blk < 4096) {
    size_t base = ((size_t)blk * 256 + threadIdx.x) * 8;
    *(bf16x8*)(Xb + base) = load8bf_rt(X, base, fp32);
  } else if (blk < 5632) {
    int w = (blk - 4096) >> 9;
    int r = (blk - 4096) & 511;
    const void* W = (w == 0) ? Wq : (w == 1) ? Wk : Wv;
    size_t base = ((size_t)r * 256 + threadIdx.x) * 8;
    *(bf16x8*)(Wb + (size_t)w * 1048576 + base) = load8bf_rt(W, base, fp32);
  } else {
    int w = blk - 5632;
    const void* Bsrc = (w == 0) ? bq : (w == 1) ? bk : bv;
    for (int i = threadIdx.x; i < 1024; i += 256)
      Bb[w * 1024 + i] = fp32 ? load1<true>(Bsrc, i) : load1<false>(Bsrc, i);
  }
}

// ---------------- QKV projection GEMM (128x256 tile, BK=32, dbuf glds16) ----
// 512 threads (8 waves: wave tile 64Mx64N, acc 4x4). LDS rows are 64B (32
// bf16), 16B seg phys = logical ^ (row&3), staged via glds16 with
// pre-swizzled global source. Dbuf 48KB. EXPLICIT vmcnt(0) drain before each
// in-loop barrier (the R7 variant lacked this and replay-corrupted).
// Grid 768 = 3z x 4nb x 64mb; XCD chunk = 96 consecutive wg.
// z<2: MFMA(A=W, B=X) -> col walks s, reg r walks hd -> 8-B Q/K stores.
// z=2: MFMA(A=X, B=W) -> reg r walks s -> 8-B packed V stores (key-swizzled).
__global__ __launch_bounds__(512, 2) void qkv_bf(
    const unsigned short* __restrict__ Xb, const unsigned short* __restrict__ Wb,
    const float* __restrict__ Bb,
    unsigned short* __restrict__ Qo, unsigned short* __restrict__ Ko,
    unsigned short* __restrict__ Vo)
{
  // XCD swizzle: nwg=768, 8 XCDs, 96 blocks/XCD chunk
  const int bid = blockIdx.x;
  const int wg  = (bid & 7) * 96 + (bid >> 3);
  const int z   = wg >> 8;           // 0..2 (matrix)
  const int rem = wg & 255;
  const int nb  = rem >> 6;          // 0..3  (W-panel, 256 cols)
  const int mb  = rem & 63;          // 0..63
  const unsigned short* W = Wb + (size_t)z * 1048576;

  __shared__ __align__(16) unsigned short Xs[2][128 * 32];
  __shared__ __align__(16) unsigned short Ws[2][256 * 32];

  const int tid  = threadIdx.x;
  const int wave = tid >> 6;        // 0..7
  const int lane = tid & 63;
  const int col  = lane & 15;
  const int quad = lane >> 4;
  const int wr = wave & 1;          // m half (64 rows)
  const int wc = wave >> 1;         // n quarter (64 cols)
  const int m0 = mb * 128;
  const int n0 = nb * 256;

  f32x4 zero4 = {0.f, 0.f, 0.f, 0.f};
  f32x4 acc[4][4];
#pragma unroll
  for (int i = 0; i < 4; ++i)
#pragma unroll
    for (int j = 0; j < 4; ++j) acc[i][j] = zero4;

  // staging: rows are 64B (4 segs). Per glds16 call (512 lanes x 16B = 8KB)
  // covers 128 rows; wave covers 16 rows (4 lanes/row).
  const int srow16 = lane >> 2;     // 0..15: row within wave's 16-row group
  const int sseg   = lane & 3;      // phys 16B seg within 64B row
  const int lseg   = sseg ^ (srow16 & 3);   // row&3 == srow16&3 (bases mult of 16)
  const unsigned short* xA  = Xb + (size_t)(m0 + wave * 16 + srow16) * DIM + lseg * 8;
  const unsigned short* wA0 = W  + (size_t)(n0 +   0 + wave * 16 + srow16) * DIM + lseg * 8;
  const unsigned short* wA1 = W  + (size_t)(n0 + 128 + wave * 16 + srow16) * DIM + lseg * 8;

  auto stage = [&](int k0, int bufn) {
    glds16(xA  + k0, Xs[bufn] + (wave * 16) * 32);
    glds16(wA0 + k0, Ws[bufn] + (wave * 16) * 32);
    glds16(wA1 + k0, Ws[bufn] + (128 + wave * 16) * 32);
  };

  stage(0, 0);   // prologue prefetch

  if (z < 2) {
    // ---- Q/K: swapped operands (A=W frag, B=X frag) ----
    for (int ks = 0; ks < 32; ++ks) {
      vm_drain();                 // own in-flight glds16 landed
      __syncthreads();            // all waves' -> buf[ks&1] ready
      if (ks < 31) stage((ks + 1) * 32, (ks + 1) & 1);
      const unsigned short* Xc = Xs[ks & 1];
      const unsigned short* Wc = Ws[ks & 1];
      bf16x8 Af[4], Bf[4];
#pragma unroll
      for (int i = 0; i < 4; ++i) {
        int ra = wr * 64 + i * 16 + col;
        Af[i] = *(const bf16x8*)(Xc + ra * 32 + (quad ^ (ra & 3)) * 8);
      }
#pragma unroll
      for (int j = 0; j < 4; ++j) {
        int rb = wc * 64 + j * 16 + col;
        Bf[j] = *(const bf16x8*)(Wc + rb * 32 + (quad ^ (rb & 3)) * 8);
      }
#pragma unroll
      for (int i = 0; i < 4; ++i)
#pragma unroll
        for (int j = 0; j < 4; ++j)
          acc[i][j] = __builtin_amdgcn_mfma_f32_16x16x32_bf16(Bf[j], Af[i], acc[i][j], 0, 0, 0);
    }

    // epilogue: lane col -> s (within 16), reg r -> hd. 8-B packed stores.
    const float oscale = (z == 0) ? QSCALE : 1.0f;
    unsigned short* Yo = (z == 0) ? Qo : Ko;
#pragma unroll
    for (int i = 0; i < 4; ++i) {
      int m = m0 + wr * 64 + i * 16 + col;
      int b = m >> 11, s = m & 2047;
#pragma unroll
      for (int j = 0; j < 4; ++j) {
        int n = n0 + wc * 64 + j * 16 + quad * 4;    // hd base (4-aligned)
        f32x4 bv4 = *(const f32x4*)(Bb + z * 1024 + n);
        int h = n >> 6, hd = n & 63;
        unsigned lo = cvtpk((acc[i][j][0] + bv4[0]) * oscale,
                            (acc[i][j][1] + bv4[1]) * oscale);
        unsigned hi = cvtpk((acc[i][j][2] + bv4[2]) * oscale,
                            (acc[i][j][3] + bv4[3]) * oscale);
        unsigned long long pk = (unsigned long long)lo | ((unsigned long long)hi << 32);
        *(unsigned long long*)(Yo + ((size_t)(b * NH + h) * SEQ + s) * HDIM + hd) = pk;
      }
    }
  } else {
    // ---- V: original orientation (A=X frag, B=W frag) ----
    for (int ks = 0; ks < 32; ++ks) {
      vm_drain();
      __syncthreads();
      if (ks < 31) stage((ks + 1) * 32, (ks + 1) & 1);
      const unsigned short* Xc = Xs[ks & 1];
      const unsigned short* Wc = Ws[ks & 1];
      bf16x8 Af[4], Bf[4];
#pragma unroll
      for (int i = 0; i < 4; ++i) {
        int ra = wr * 64 + i * 16 + col;
        Af[i] = *(const bf16x8*)(Xc + ra * 32 + (quad ^ (ra & 3)) * 8);
      }
#pragma unroll
      for (int j = 0; j < 4; ++j) {
        int rb = wc * 64 + j * 16 + col;
        Bf[j] = *(const bf16x8*)(Wc + rb * 32 + (quad ^ (rb & 3)) * 8);
      }
#pragma unroll
      for (int i = 0; i < 4; ++i)
#pragma unroll
        for (int j = 0; j < 4; ++j)
          acc[i][j] = __builtin_amdgcn_mfma_f32_16x16x32_bf16(Af[i], Bf[j], acc[i][j], 0, 0, 0);
    }

    // V epilogue: transposed [bh][hd][SEQ], KEY-SWIZZLED (4-key chunk -> vswz)
#pragma unroll
    for (int i = 0; i < 4; ++i) {
#pragma unroll
      for (int j = 0; j < 4; ++j) {
        int n = n0 + wc * 64 + j * 16 + col;
        float bvf = Bb[2 * 1024 + n];
        int h = n >> 6, hd = n & 63;
        int mbase = m0 + wr * 64 + i * 16 + quad * 4;
        int b = mbase >> 11, s = mbase & 2047;
        unsigned lo = cvtpk(acc[i][j][0] + bvf, acc[i][j][1] + bvf);
        unsigned hi = cvtpk(acc[i][j][2] + bvf, acc[i][j][3] + bvf);
        unsigned long long pk = (unsigned long long)lo | ((unsigned long long)hi << 32);
        *(unsigned long long*)(Vo + ((size_t)(b * NH + h) * HDIM + hd) * SEQ + vswz(s)) = pk;
      }
    }
  }
}

// ---------------- fallback QKV (raw inputs, flag-gated) ----------------
#define XS_STRIDE 40
template <bool FP32>
__global__ __launch_bounds__(256) void qkv_any(
    const void* __restrict__ X,
    const void* __restrict__ Wq, const void* __restrict__ bq,
    const void* __restrict__ Wk, const void* __restrict__ bk,
    const void* __restrict__ Wv, const void* __restrict__ bv,
    unsigned short* __restrict__ Qo, unsigned short* __restrict__ Ko,
    unsigned short* __restrict__ Vo, const int* __restrict__ flag)
{
  if (*flag != (FP32 ? 1 : 0)) return;
  const int z = blockIdx.z;
  const void* W    = (z == 0) ? Wq : (z == 1) ? Wk : Wv;
  const void* bias = (z == 0) ? bq : (z == 1) ? bk : bv;

  __shared__ __align__(16) unsigned short Xs[128 * XS_STRIDE];
  __shared__ __align__(16) unsigned short Ws[128 * XS_STRIDE];

  const int tid  = threadIdx.x;
  const int wave = tid >> 6;
  const int lane = tid & 63;
  const int col  = lane & 15;
  const int quad = lane >> 4;
  const int wr = wave & 1;
  const int wc = wave >> 1;
  const int m0 = blockIdx.x * 128;
  const int n0 = blockIdx.y * 128;

  f32x4 zero4 = {0.f, 0.f, 0.f, 0.f};
  f32x4 acc[4][4];
#pragma unroll
  for (int i = 0; i < 4; ++i)
#pragma unroll
    for (int j = 0; j < 4; ++j) acc[i][j] = zero4;

  const int srow = tid >> 2;
  const int sseg = (tid & 3) << 3;

  for (int k0 = 0; k0 < DIM; k0 += 32) {
    __syncthreads();
#pragma unroll
    for (int a = 0; a < 2; ++a) {
      int r = a * 64 + srow;
      *(bf16x8*)(Xs + r * XS_STRIDE + sseg) = load8bf<FP32>(X, (size_t)(m0 + r) * DIM + k0 + sseg);
      *(bf16x8*)(Ws + r * XS_STRIDE + sseg) = load8bf<FP32>(W, (size_t)(n0 + r) * DIM + k0 + sseg);
    }
    __syncthreads();

    bf16x8 Af[4], Bf[4];
#pragma unroll
    for (int i = 0; i < 4; ++i)
      Af[i] = *(const bf16x8*)(Xs + (wr * 64 + i * 16 + col) * XS_STRIDE + quad * 8);
#pragma unroll
    for (int j = 0; j < 4; ++j)
      Bf[j] = *(const bf16x8*)(Ws + (wc * 64 + j * 16 + col) * XS_STRIDE + quad * 8);
#pragma unroll
    for (int i = 0; i < 4; ++i)
#pragma unroll
      for (int j = 0; j < 4; ++j)
        acc[i][j] = __builtin_amdgcn_mfma_f32_16x16x32_bf16(Af[i], Bf[j], acc[i][j], 0, 0, 0);
  }

  const float oscale = (z == 0) ? QSCALE : 1.0f;
  if (z < 2) {
    unsigned short* Yo = (z == 0) ? Qo : Ko;
#pragma unroll
    for (int i = 0; i < 4; ++i) {
#pragma unroll
      for (int j = 0; j < 4; ++j) {
        int n = n0 + wc * 64 + j * 16 + col;
        float bvf = load1<FP32>(bias, n);
        int h = n >> 6, hd = n & 63;
#pragma unroll
        for (int r = 0; r < 4; ++r) {
          int m = m0 + wr * 64 + i * 16 + quad * 4 + r;
          int b = m >> 11, s = m & 2047;
          Yo[((size_t)(b * NH + h) * SEQ + s) * HDIM + hd] = f2bf((acc[i][j][r] + bvf) * oscale);
        }
      }
    }
  } else {
#pragma unroll
    for (int i = 0; i < 4; ++i) {
#pragma unroll
      for (int j = 0; j < 4; ++j) {
        int n = n0 + wc * 64 + j * 16 + col;
        float bvf = load1<FP32>(bias, n);
        int h = n >> 6, hd = n & 63;
        int mbase = m0 + wr * 64 + i * 16 + quad * 4;
        int b = mbase >> 11, s = mbase & 2047;
        unsigned long long pk = 0;
#pragma unroll
        for (int r = 0; r < 4; ++r)
          pk |= (unsigned long long)f2bf(acc[i][j][r] + bvf) << (16 * r);
        *(unsigned long long*)(Vo + ((size_t)(b * NH + h) * HDIM + hd) * SEQ + vswz(s)) = pk;
      }
    }
  }
}

// ---------------- flash attention (single launch, runtime fp32) -----------
// grid (8, 64), block 512 (8 waves); wave = 32 queries (2 column groups
// sharing K/V fragment reads). 256 queries/block. Scores transposed (S^T).
// K LDS: 2 x [128 rows x 128B], 16B seg phys = logical ^ (row&7)  (glds16)
// V LDS: 2 x [64 rows x 256B] (keys pre-swizzled in ws), seg phys = logical ^ (row&15)
// Double-buffered: prefetch kt+1 issued before compute on kt; explicit
// vmcnt(0) drain + barrier guarantees buf[kt&1] ready.
// ALL 16 Bv fragments hoisted before softmax -> PV loop reads no LDS.
__global__ __launch_bounds__(512, 2) void attn_kernel(
    const unsigned short* __restrict__ Q,
    const unsigned short* __restrict__ K,
    const unsigned short* __restrict__ Vt,   // [bh][hd][SEQ], key-swizzled
    const void* __restrict__ mask,
    void* __restrict__ OutV, const int* __restrict__ flag)
{
  const bool fp32 = (*flag != 0);

  __shared__ __align__(16) unsigned short Ks[2 * 128 * 64];
  __shared__ __align__(16) unsigned short Vs[2 * 64 * 128];
  __shared__ __align__(16) float Msall[SEQ];

  const int tid  = threadIdx.x;
  const int wave = tid >> 6;        // 0..7
  const int lane = tid & 63;
  const int col  = lane & 15;
  const int quad = lane >> 4;
  const int qt = blockIdx.x;        // 0..7
  const int bh = blockIdx.y;
  const int b  = bh >> 4;
  const int h  = bh & 15;

  const unsigned short* Qb = Q  + (size_t)bh * SEQ * HDIM;
  const unsigned short* Kb = K  + (size_t)bh * SEQ * HDIM;
  const unsigned short* Vb = Vt + (size_t)bh * HDIM * SEQ;

  // ---- stage mask row once (pre-multiplied by LOG2E); 4 floats/thread ----
  {
    if (fp32) {
      f32x4 a = *(const f32x4*)((const float*)mask + (size_t)b * SEQ + tid * 4);
#pragma unroll
      for (int j = 0; j < 4; ++j) a[j] *= LOG2E;
      *(f32x4*)(Msall + tid * 4) = a;
    } else {
      bf16x4 v = *(const bf16x4*)((const unsigned short*)mask + (size_t)b * SEQ + tid * 4);
      f32x4 a;
#pragma unroll
      for (int j = 0; j < 4; ++j) a[j] = bf2f((unsigned short)v[j]) * LOG2E;
      *(f32x4*)(Msall + tid * 4) = a;
    }
  }

  // ---- Q fragments: two 16-query groups per wave ----
  const int qrow0 = qt * 256 + wave * 32 + col;
  const int qrow1 = qrow0 + 16;
  const bf16x8 Qf00 = *(const bf16x8*)(Qb + (size_t)qrow0 * HDIM + quad * 8);
  const bf16x8 Qf01 = *(const bf16x8*)(Qb + (size_t)qrow0 * HDIM + 32 + quad * 8);
  const bf16x8 Qf10 = *(const bf16x8*)(Qb + (size_t)qrow1 * HDIM + quad * 8);
  const bf16x8 Qf11 = *(const bf16x8*)(Qb + (size_t)qrow1 * HDIM + 32 + quad * 8);

  const f32x4 z4 = {0.f, 0.f, 0.f, 0.f};
  f32x4 Oacc0[4], Oacc1[4];
  f32x4 Osum0 = z4, Osum1 = z4;
#pragma unroll
  for (int t = 0; t < 4; ++t) { Oacc0[t] = z4; Oacc1[t] = z4; }
  float mrun0 = -1e30f, mrun1 = -1e30f;

  union { bf16x8 v; unsigned u[4]; } ones;
#pragma unroll
  for (int i = 0; i < 4; ++i) ones.u[i] = 0x3F803F80u;   // bf16 1.0 x2

  // ---- loop-invariant staging addresses ----
  const int krow_in = lane >> 3;            // 0..7
  const int kphys   = lane & 7;             // 16B seg within 128B row
  const int klseg   = kphys ^ krow_in;      // loop/a-invariant
  const unsigned short* kSrc0 = Kb + (size_t)(wave * 16 + 0 + krow_in) * HDIM + klseg * 8;
  const unsigned short* kSrc1 = Kb + (size_t)(wave * 16 + 8 + krow_in) * HDIM + klseg * 8;
  const int vrow_in = lane >> 4;            // 0..3
  const int vphys   = lane & 15;            // 16B seg within 256B row
  const int vrowA0  = wave * 8 + 0 + vrow_in;
  const int vrowA1  = wave * 8 + 4 + vrow_in;
  const unsigned short* vSrc0 = Vb + (size_t)vrowA0 * SEQ + (vphys ^ (vrowA0 & 15)) * 8;
  const unsigned short* vSrc1 = Vb + (size_t)vrowA1 * SEQ + (vphys ^ (vrowA1 & 15)) * 8;

  auto stage = [&](int ktn, int bufn) {
    unsigned short* Kdst = Ks + bufn * (128 * 64) + (wave * 16) * 64;
    unsigned short* Vdst = Vs + bufn * (64 * 128) + (wave * 8) * 128;
    const size_t ko = (size_t)ktn * 128 * HDIM;
    const size_t vo = (size_t)ktn * 128;
    glds16(kSrc0 + ko, Kdst);
    glds16(kSrc1 + ko, Kdst + 8 * 64);
    glds16(vSrc0 + vo, Vdst);
    glds16(vSrc1 + vo, Vdst + 4 * 128);
  };

  stage(0, 0);   // prologue prefetch

  for (int kt = 0; kt < 16; ++kt) {
    vm_drain();                             // own in-flight glds16 landed
    __syncthreads();                        // all waves' -> buf[kt&1] ready
    if (kt < 15) stage(kt + 1, (kt + 1) & 1);

    const unsigned short* Kcur = Ks + (kt & 1) * (128 * 64);
    const unsigned short* Vcur = Vs + (kt & 1) * (64 * 128);
    const float* Mc = Msall + kt * 128;

    // --- QK^T (S^T, log2 domain): C initialized with mask; K frags shared ---
    f32x4 st0[8], st1[8];
    __builtin_amdgcn_s_setprio(1);
#pragma unroll
    for (int t = 0; t < 8; ++t) {
      const unsigned short* kr = Kcur + (t * 16 + col) * 64;
      bf16x8 Ka = *(const bf16x8*)(kr + (quad ^ (col & 7)) * 8);
      bf16x8 Kc = *(const bf16x8*)(kr + ((4 + quad) ^ (col & 7)) * 8);
      f32x4 c = *(const f32x4*)(Mc + t * 16 + quad * 4);   // mask*log2e as C
      f32x4 d0 = c, d1 = c;
      d0 = __builtin_amdgcn_mfma_f32_16x16x32_bf16(Ka, Qf00, d0, 0, 0, 0);
      d0 = __builtin_amdgcn_mfma_f32_16x16x32_bf16(Kc, Qf01, d0, 0, 0, 0);
      d1 = __builtin_amdgcn_mfma_f32_16x16x32_bf16(Ka, Qf10, d1, 0, 0, 0);
      d1 = __builtin_amdgcn_mfma_f32_16x16x32_bf16(Kc, Qf11, d1, 0, 0, 0);
      st0[t] = d0; st1[t] = d1;
    }
    __builtin_amdgcn_s_setprio(0);

    // --- hoist ALL V fragments: ds_reads complete under softmax; PV is
    //     LDS-free (16 bf16x8 = 32 VGPR; total ~116 <= 128, occupancy holds) ---
    bf16x8 Bv[4][4];
#pragma unroll
    for (int tp = 0; tp < 4; ++tp)
#pragma unroll
      for (int t2 = 0; t2 < 4; ++t2)
        Bv[tp][t2] = *(const bf16x8*)(Vcur + (t2 * 16 + col) * 128 + ((tp * 4 + quad) ^ col) * 8);

    // --- online softmax (per query = col; keys in-lane), defer-max ---
    float pm0, pm1;
    {
      f32x4 m40, m41;
#pragma unroll
      for (int r = 0; r < 4; ++r) {
        float a0 = fmaxf(fmaxf(st0[0][r], st0[1][r]), st0[2][r]);
        a0 = fmaxf(fmaxf(a0, st0[3][r]), st0[4][r]);
        a0 = fmaxf(fmaxf(a0, st0[5][r]), st0[6][r]);
        m40[r] = fmaxf(a0, st0[7][r]);
        float a1 = fmaxf(fmaxf(st1[0][r], st1[1][r]), st1[2][r]);
        a1 = fmaxf(fmaxf(a1, st1[3][r]), st1[4][r]);
        a1 = fmaxf(fmaxf(a1, st1[5][r]), st1[6][r]);
        m41[r] = fmaxf(a1, st1[7][r]);
      }
      pm0 = fmaxf(fmaxf(fmaxf(m40[0], m40[1]), m40[2]), m40[3]);
      pm1 = fmaxf(fmaxf(fmaxf(m41[0], m41[1]), m41[2]), m41[3]);
    }
    pm0 = fmaxf(pm0, __shfl_xor(pm0, 16, 64));
    pm0 = fmaxf(pm0, __shfl_xor(pm0, 32, 64));
    pm1 = fmaxf(pm1, __shfl_xor(pm1, 16, 64));
    pm1 = fmaxf(pm1, __shfl_xor(pm1, 32, 64));

    if (!__all((pm0 - mrun0 <= 8.0f) && (pm1 - mrun1 <= 8.0f))) {
      float mn0 = fmaxf(mrun0, pm0), mn1 = fmaxf(mrun1, pm1);
      float a0 = __builtin_amdgcn_exp2f(mrun0 - mn0);
      float a1 = __builtin_amdgcn_exp2f(mrun1 - mn1);
      mrun0 = mn0; mrun1 = mn1;
      float av0[4], av1[4];
#pragma unroll
      for (int r = 0; r < 4; ++r) {
        av0[r] = __shfl(a0, quad * 4 + r, 64);
        av1[r] = __shfl(a1, quad * 4 + r, 64);
      }
#pragma unroll
      for (int t = 0; t < 4; ++t)
#pragma unroll
        for (int r = 0; r < 4; ++r) {
          Oacc0[t][r] *= av0[r];
          Oacc1[t][r] *= av1[r];
        }
#pragma unroll
      for (int r = 0; r < 4; ++r) { Osum0[r] *= av0[r]; Osum1[r] *= av1[r]; }
    }

#pragma unroll
    for (int t = 0; t < 8; ++t)
#pragma unroll
      for (int r = 0; r < 4; ++r) {
        st0[t][r] = __builtin_amdgcn_exp2f(st0[t][r] - mrun0);
        st1[t][r] = __builtin_amdgcn_exp2f(st1[t][r] - mrun1);
      }

    // --- PV + row-sum via MFMA; P straight from score regs; LDS-free ---
    __builtin_amdgcn_s_setprio(1);
#pragma unroll
    for (int tp = 0; tp < 4; ++tp) {
      union { bf16x8 v; unsigned u[4]; } A0, A1;
      A0.u[0] = cvtpk(st0[2 * tp][0],     st0[2 * tp][1]);
      A0.u[1] = cvtpk(st0[2 * tp][2],     st0[2 * tp][3]);
      A0.u[2] = cvtpk(st0[2 * tp + 1][0], st0[2 * tp + 1][1]);
      A0.u[3] = cvtpk(st0[2 * tp + 1][2], st0[2 * tp + 1][3]);
      A1.u[0] = cvtpk(st1[2 * tp][0],     st1[2 * tp][1]);
      A1.u[1] = cvtpk(st1[2 * tp][2],     st1[2 * tp][3]);
      A1.u[2] = cvtpk(st1[2 * tp + 1][0], st1[2 * tp + 1][1]);
      A1.u[3] = cvtpk(st1[2 * tp + 1][2], st1[2 * tp + 1][3]);
      Osum0 = __builtin_amdgcn_mfma_f32_16x16x32_bf16(A0.v, ones.v, Osum0, 0, 0, 0);
      Osum1 = __builtin_amdgcn_mfma_f32_16x16x32_bf16(A1.v, ones.v, Osum1, 0, 0, 0);
#pragma unroll
      for (int t2 = 0; t2 < 4; ++t2) {
        Oacc0[t2] = __builtin_amdgcn_mfma_f32_16x16x32_bf16(A0.v, Bv[tp][t2], Oacc0[t2], 0, 0, 0);
        Oacc1[t2] = __builtin_amdgcn_mfma_f32_16x16x32_bf16(A1.v, Bv[tp][t2], Oacc1[t2], 0, 0, 0);
      }
    }
    __builtin_amdgcn_s_setprio(0);
  }

  // epilogue: rows q = quad*4+r within each 16-query group; l sits in Osum rows
  float liv0[4], liv1[4];
#pragma unroll
  for (int r = 0; r < 4; ++r) { liv0[r] = 1.0f / Osum0[r]; liv1[r] = 1.0f / Osum1[r]; }
#pragma unroll
  for (int t2 = 0; t2 < 4; ++t2) {
#pragma unroll
    for (int r = 0; r < 4; ++r) {
      int q0 = qt * 256 + wave * 32 + quad * 4 + r;
      int q1 = q0 + 16;
      float v0 = Oacc0[t2][r] * liv0[r];
      float v1 = Oacc1[t2][r] * liv1[r];
      v0 = (v0 == v0) ? v0 : 0.0f;
      v1 = (v1 == v1) ? v1 : 0.0f;
      size_t o0 = ((size_t)b * SEQ + q0) * DIM + h * HDIM + t2 * 16 + col;
      size_t o1 = ((size_t)b * SEQ + q1) * DIM + h * HDIM + t2 * 16 + col;
      if (fp32) {
        ((float*)OutV)[o0] = v0;
        ((float*)OutV)[o1] = v1;
      } else {
        ((unsigned short*)OutV)[o0] = f2bf(v0);
        ((unsigned short*)OutV)[o1] = f2bf(v1);
      }
    }
  }
}

extern "C" void kernel_launch(void* const* d_in, const int* in_sizes, int n_in,
                              void* d_out, int out_size, void* d_ws, size_t ws_size,
                              hipStream_t stream) {
  const void* X    = d_in[0];
  const void* mask = d_in[1];
  const void* Wq   = d_in[2];
  const void* bq   = d_in[3];
  const void* Wk   = d_in[4];
  const void* bk   = d_in[5];
  const void* Wv   = d_in[6];
  const void* bv   = d_in[7];

  unsigned char* ws = (unsigned char*)d_ws;
  unsigned short* Qw = (unsigned short*)ws;
  unsigned short* Kw = Qw + QKV_ELEMS;
  unsigned short* Vw = Kw + QKV_ELEMS;
  int* flag = (int*)(ws + WS_FLAG);

  detect_dtype<<<1, 1024, 0, stream>>>((const unsigned short*)X, flag);

  if (ws_size >= WS_NEED) {
    convert_all_u<<<5635, 256, 0, stream>>>(X, Wq, Wk, Wv, bq, bk, bv, ws, flag);
    qkv_bf<<<768, 512, 0, stream>>>(
        (const unsigned short*)(ws + WS_XBF), (const unsigned short*)(ws + WS_WBF),
        (const float*)(ws + WS_BF32), Qw, Kw, Vw);
  } else {
    qkv_any<false><<<dim3(64, 8, 3), 256, 0, stream>>>(X, Wq, bq, Wk, bk, Wv, bv, Qw, Kw, Vw, flag);
    qkv_any<true ><<<dim3(64, 8, 3), 256, 0, stream>>>(X, Wq, bq, Wk, bk, Wv, bv, Qw, Kw, Vw, flag);
  }

  attn_kernel<<<dim3(8, 64), 512, 0, stream>>>(Qw, Kw, Vw, mask, d_out, flag);
}